// Round 1
// baseline (1845.042 us; speedup 1.0000x reference)
//
#include <hip/hip_runtime.h>
#include <math.h>

// Problem constants
// D=4096 K=512 HOP=512 WIN=16384 R=25 B=128 K2=128 DY=128 K3=256 DX=25 NRY=193 M=128
// ws layout (bytes):
//   zx    @ 0          : 128*25*512*4   = 6,553,600
//   h2    @ 6,553,600  : 128*256*193*4  = 25,288,704
//   w2t   @ 31,842,304 : 25*128*256*4   = 3,276,800
//   part  @ 35,119,104 : 128*16384*4    = 8,388,608
// total 43,507,712 B

// ---------------- K0: transpose conv2_w (K3,K2,DX) -> (DX,K2,K3) ----------------
__global__ void k0_w2t(const float* __restrict__ w2, float* __restrict__ w2t) {
    int i = blockIdx.x * 256 + threadIdx.x;      // 0 .. 819199
    int k3 = i & 255;
    int k2 = (i >> 8) & 127;
    int dx = i >> 15;
    w2t[i] = w2[(k3 * 128 + k2) * 25 + dx];
}

// ---------------- K1: spec GEMM + |.|^2 + log -> zx ----------------
// C(3200x1024) = windows(3200x4096) @ filters(4096x1024); zx = log(pairs)
__global__ __launch_bounds__(256)
void k1_spec(const float* __restrict__ x, const float* __restrict__ filt,
             float* __restrict__ zx) {
    __shared__ float As[16 * 72];   // [k][row]
    __shared__ float Bs[16 * 72];   // [k][col]
    const int t  = threadIdx.x;
    const int m0 = blockIdx.y * 64;
    const int n0 = blockIdx.x * 64;

    // A-load mapping: row = t&63, 4 cols starting at (t>>6)*4
    const int lrow = t & 63;
    const int lc4  = (t >> 6) << 2;
    const int rg   = m0 + lrow;
    const int lb   = rg / 25;
    const int lr   = rg % 25;
    const float* xA = x + lb * 16384 + lr * 512 + lc4;

    // B-load mapping: 4 cols at (t&15)*4 of filter row (t>>4)
    const int ln4 = (t & 15) << 2;
    const int lkk = t >> 4;
    const float* fB = filt + lkk * 1024 + n0 + ln4;

    const int ty = t >> 4, tx = t & 15;

    float c[4][4];
#pragma unroll
    for (int i = 0; i < 4; i++)
#pragma unroll
        for (int j = 0; j < 4; j++) c[i][j] = 0.f;

    for (int k0 = 0; k0 < 4096; k0 += 16) {
        __syncthreads();
        float4 av = *(const float4*)(xA + k0);
        As[(lc4 + 0) * 72 + lrow] = av.x;
        As[(lc4 + 1) * 72 + lrow] = av.y;
        As[(lc4 + 2) * 72 + lrow] = av.z;
        As[(lc4 + 3) * 72 + lrow] = av.w;
        float4 bv = *(const float4*)(fB + (size_t)k0 * 1024);
        *(float4*)&Bs[lkk * 72 + ln4] = bv;
        __syncthreads();
#pragma unroll
        for (int kk = 0; kk < 16; kk++) {
            float4 a4 = *(const float4*)&As[kk * 72 + ty * 4];
            float4 b4 = *(const float4*)&Bs[kk * 72 + tx * 4];
            float a[4] = {a4.x, a4.y, a4.z, a4.w};
            float b[4] = {b4.x, b4.y, b4.z, b4.w};
#pragma unroll
            for (int i = 0; i < 4; i++)
#pragma unroll
                for (int j = 0; j < 4; j++)
                    c[i][j] = fmaf(a[i], b[j], c[i][j]);
        }
    }
    // epilogue: pairs (2p, 2p+1) -> zx[row][ (n0 + tx*4)/2 + p ]
#pragma unroll
    for (int i = 0; i < 4; i++) {
        int row = m0 + ty * 4 + i;
#pragma unroll
        for (int p = 0; p < 2; p++) {
            float re = c[i][2 * p];
            float im = c[i][2 * p + 1];
            float pw = fmaf(re, re, fmaf(im, im, 1e-14f));
            zx[row * 512 + (n0 >> 1) + tx * 2 + p] = logf(pw);
        }
    }
}

// ---------------- K2: fused conv1(relu) + conv2(relu) -> h2 ----------------
// block = (yt in 0..6, b in 0..127); computes h2[b, 0:256, yt*28 .. +28)
__global__ __launch_bounds__(256)
void k2_conv(const float* __restrict__ zx, const float* __restrict__ w1,
             const float* __restrict__ w2t, float* __restrict__ h2) {
    __shared__ float zxl[25 * 184];   // zx[b, dx, c0 .. c0+182)
    __shared__ float hd[128 * 29];    // Hdx[k2][yy], pitch 29
    const int t  = threadIdx.x;
    const int yt = blockIdx.x;        // 0..6
    const int b  = blockIdx.y;        // 0..127
    const int c0 = yt * 56;           // = 2*y0, y0 = yt*28

    for (int idx = t; idx < 25 * 182; idx += 256) {
        int dxr = idx / 182, cc = idx % 182;
        int c = c0 + cc;
        zxl[dxr * 184 + cc] = (c < 512) ? zx[(b * 25 + dxr) * 512 + c] : 0.f;
    }

    const int grp = t >> 2;       // 0..63
    const int yg  = t & 3;        // 0..3
    const int yy0 = yg * 7;
    const int k2a = grp * 2;      // A-step: rows k2a, k2a+1
    const int k3a = grp * 4;      // B-step: k3a .. k3a+3

    float acc[4][7];
#pragma unroll
    for (int i = 0; i < 4; i++)
#pragma unroll
        for (int j = 0; j < 7; j++) acc[i][j] = 0.f;

    const float4* w1a = (const float4*)(w1 + k2a * 128);
    const float4* w1b = (const float4*)(w1 + (k2a + 1) * 128);

    for (int dx = 0; dx < 25; dx++) {
        __syncthreads();   // hd safe to overwrite; zxl visible (first iter)
        // ---- A-step: Hdx[k2][yy] = relu(sum_dy w1[k2][dy] * zx[dx][2yy+dy])
        float a0[7], a1[7];
#pragma unroll
        for (int j = 0; j < 7; j++) { a0[j] = 0.f; a1[j] = 0.f; }
        const float* zrow = &zxl[dx * 184 + 2 * yy0];
        for (int dq = 0; dq < 32; dq++) {
            float4 wv0 = w1a[dq];
            float4 wv1 = w1b[dq];
#pragma unroll
            for (int u = 0; u < 4; u++) {
                int dy = dq * 4 + u;
                float wa = ((const float*)&wv0)[u];
                float wb = ((const float*)&wv1)[u];
#pragma unroll
                for (int j = 0; j < 7; j++) {
                    float z = zrow[2 * j + dy];
                    a0[j] = fmaf(wa, z, a0[j]);
                    a1[j] = fmaf(wb, z, a1[j]);
                }
            }
        }
#pragma unroll
        for (int j = 0; j < 7; j++) {
            hd[k2a * 29 + yy0 + j]       = fmaxf(a0[j], 0.f);
            hd[(k2a + 1) * 29 + yy0 + j] = fmaxf(a1[j], 0.f);
        }
        __syncthreads();
        // ---- B-step: acc[k3][yy] += sum_k2 w2t[dx][k2][k3] * Hdx[k2][yy]
        const float4* w2p = (const float4*)(w2t + dx * 32768);
#pragma unroll 2
        for (int k2 = 0; k2 < 128; k2++) {
            float4 wv = w2p[k2 * 64 + grp];
            float h[7];
#pragma unroll
            for (int j = 0; j < 7; j++) h[j] = hd[k2 * 29 + yy0 + j];
#pragma unroll
            for (int j = 0; j < 7; j++) {
                acc[0][j] = fmaf(wv.x, h[j], acc[0][j]);
                acc[1][j] = fmaf(wv.y, h[j], acc[1][j]);
                acc[2][j] = fmaf(wv.z, h[j], acc[2][j]);
                acc[3][j] = fmaf(wv.w, h[j], acc[3][j]);
            }
        }
    }
    // store h2 with relu
#pragma unroll
    for (int i = 0; i < 4; i++) {
        int k3 = k3a + i;
#pragma unroll
        for (int j = 0; j < 7; j++) {
            int y = yt * 28 + yy0 + j;
            if (y < 193)
                h2[(b * 256 + k3) * 193 + y] = fmaxf(acc[i][j], 0.f);
        }
    }
}

// ---------------- K4: y partials = h2(128x49408) @ beta^T, k-split 128 ----------------
__global__ __launch_bounds__(256)
void k4_beta(const float* __restrict__ h2, const float* __restrict__ beta,
             float* __restrict__ part) {
    __shared__ float As[2 * 132];
    __shared__ float Bs[2 * 132];
    const int t  = threadIdx.x;
    const int s  = blockIdx.x;     // 0..127
    const int ks = s * 386;
    const int lrow = t >> 1;       // 0..127
    const int lkk  = t & 1;
    const int tx = t & 15, ty = t >> 4;

    float acc[8][8];
#pragma unroll
    for (int i = 0; i < 8; i++)
#pragma unroll
        for (int j = 0; j < 8; j++) acc[i][j] = 0.f;

    const float* hrow = h2   + (size_t)lrow * 49408 + ks + lkk;
    const float* brow = beta + (size_t)lrow * 49408 + ks + lkk;

    for (int c0 = 0; c0 < 386; c0 += 2) {
        __syncthreads();
        As[lkk * 132 + lrow] = hrow[c0];
        Bs[lkk * 132 + lrow] = brow[c0];
        __syncthreads();
#pragma unroll
        for (int kk = 0; kk < 2; kk++) {
            float4 a0 = *(const float4*)&As[kk * 132 + ty * 8];
            float4 a1 = *(const float4*)&As[kk * 132 + ty * 8 + 4];
            float4 b0 = *(const float4*)&Bs[kk * 132 + tx * 8];
            float4 b1 = *(const float4*)&Bs[kk * 132 + tx * 8 + 4];
            float a[8] = {a0.x, a0.y, a0.z, a0.w, a1.x, a1.y, a1.z, a1.w};
            float b[8] = {b0.x, b0.y, b0.z, b0.w, b1.x, b1.y, b1.z, b1.w};
#pragma unroll
            for (int i = 0; i < 8; i++)
#pragma unroll
                for (int j = 0; j < 8; j++)
                    acc[i][j] = fmaf(a[i], b[j], acc[i][j]);
        }
    }
    float* pp = part + (size_t)s * 16384;
#pragma unroll
    for (int i = 0; i < 8; i++)
#pragma unroll
        for (int j = 0; j < 8; j++)
            pp[(ty * 8 + i) * 128 + tx * 8 + j] = acc[i][j];
}

// ---------------- K5: reduce partials ----------------
__global__ void k5_red(const float* __restrict__ part, float* __restrict__ out) {
    int i = blockIdx.x * 256 + threadIdx.x;   // 0..16383
    float s = 0.f;
    for (int k = 0; k < 128; k++) s += part[(size_t)k * 16384 + i];
    out[i] = s;
}

extern "C" void kernel_launch(void* const* d_in, const int* in_sizes, int n_in,
                              void* d_out, int out_size, void* d_ws, size_t ws_size,
                              hipStream_t stream) {
    const float* x    = (const float*)d_in[0];
    const float* filt = (const float*)d_in[1];
    const float* w1   = (const float*)d_in[2];
    const float* w2   = (const float*)d_in[3];
    const float* beta = (const float*)d_in[4];
    float* out = (float*)d_out;

    char* ws = (char*)d_ws;
    float* zx   = (float*)(ws + 0);
    float* h2   = (float*)(ws + 6553600);
    float* w2t  = (float*)(ws + 31842304);
    float* part = (float*)(ws + 35119104);

    k0_w2t<<<3200, 256, 0, stream>>>(w2, w2t);
    k1_spec<<<dim3(16, 50), 256, 0, stream>>>(x, filt, zx);
    k2_conv<<<dim3(7, 128), 256, 0, stream>>>(zx, w1, w2t, h2);
    k4_beta<<<128, 256, 0, stream>>>(h2, beta, part);
    k5_red<<<64, 256, 0, stream>>>(part, out);
}

// Round 2
// 882.575 us; speedup vs baseline: 2.0905x; 2.0905x over previous
//
#include <hip/hip_runtime.h>
#include <hip/hip_bf16.h>
#include <math.h>

// D=4096 K=512 HOP=512 WIN=16384 DX=25 B=128 K2=128 DY=128 K3=256 Y=193 M=128
// ws layout (bytes):
//   zxb  @ 0          : 128*25*512*2   = 3,276,800   (bf16 zx)
//   h2b  @ 3,276,800  : 128*256*193*2  = 12,644,352  (bf16 h2)
//   w1b  @ 15,921,152 : 128*128*2      = 32,768      (bf16 w1 [k2][dy])
//   w2b  @ 15,953,920 : 25*256*128*2   = 1,638,400   (bf16 w2 [dx][k3][k2])
//   part @ 17,592,320 : 128*16384*4    = 8,388,608
// total 25,980,928 B

typedef __attribute__((ext_vector_type(8))) short s8v;    // 8 bf16 = 4 VGPR
typedef __attribute__((ext_vector_type(16))) float f16v;  // 32x32 acc

__device__ inline ushort f2bf(float f) {
    union { float f; unsigned u; } v; v.f = f;
    unsigned u = v.u;
    return (ushort)((u + 0x7FFFu + ((u >> 16) & 1u)) >> 16);
}
__device__ inline float bf2f(ushort u) {
    union { unsigned u; float f; } v; v.u = ((unsigned)u) << 16;
    return v.f;
}

// ---------------- K0a: w1 -> bf16 [k2][dy] ----------------
__global__ void k0a_w1b(const float* __restrict__ w1, ushort* __restrict__ w1b) {
    int i = blockIdx.x * 256 + threadIdx.x;   // 0..16383
    w1b[i] = f2bf(w1[i]);
}

// ---------------- K0b: w2 (K3,K2,DX) -> bf16 [dx][k3][k2] ----------------
__global__ void k0b_w2b(const float* __restrict__ w2, ushort* __restrict__ w2b) {
    int i = blockIdx.x * 256 + threadIdx.x;   // 0..819199
    int k2 = i & 127;
    int k3 = (i >> 7) & 255;
    int dx = i >> 15;
    w2b[i] = f2bf(w2[(k3 * 128 + k2) * 25 + dx]);
}

// ---------------- K1: spec GEMM (fp32) + |.|^2 + log -> zxb (bf16) ----------------
__global__ __launch_bounds__(256)
void k1_spec(const float* __restrict__ x, const float* __restrict__ filt,
             ushort* __restrict__ zxb) {
    __shared__ float As[16 * 72];
    __shared__ float Bs[16 * 72];
    const int t  = threadIdx.x;
    const int m0 = blockIdx.y * 64;
    const int n0 = blockIdx.x * 64;

    const int lrow = t & 63;
    const int lc4  = (t >> 6) << 2;
    const int rg   = m0 + lrow;
    const int lb   = rg / 25;
    const int lr   = rg % 25;
    const float* xA = x + lb * 16384 + lr * 512 + lc4;

    const int ln4 = (t & 15) << 2;
    const int lkk = t >> 4;
    const float* fB = filt + lkk * 1024 + n0 + ln4;

    const int ty = t >> 4, tx = t & 15;

    float c[4][4];
#pragma unroll
    for (int i = 0; i < 4; i++)
#pragma unroll
        for (int j = 0; j < 4; j++) c[i][j] = 0.f;

    for (int k0 = 0; k0 < 4096; k0 += 16) {
        __syncthreads();
        float4 av = *(const float4*)(xA + k0);
        As[(lc4 + 0) * 72 + lrow] = av.x;
        As[(lc4 + 1) * 72 + lrow] = av.y;
        As[(lc4 + 2) * 72 + lrow] = av.z;
        As[(lc4 + 3) * 72 + lrow] = av.w;
        float4 bv = *(const float4*)(fB + (size_t)k0 * 1024);
        *(float4*)&Bs[lkk * 72 + ln4] = bv;
        __syncthreads();
#pragma unroll
        for (int kk = 0; kk < 16; kk++) {
            float4 a4 = *(const float4*)&As[kk * 72 + ty * 4];
            float4 b4 = *(const float4*)&Bs[kk * 72 + tx * 4];
            float a[4] = {a4.x, a4.y, a4.z, a4.w};
            float b[4] = {b4.x, b4.y, b4.z, b4.w};
#pragma unroll
            for (int i = 0; i < 4; i++)
#pragma unroll
                for (int j = 0; j < 4; j++)
                    c[i][j] = fmaf(a[i], b[j], c[i][j]);
        }
    }
#pragma unroll
    for (int i = 0; i < 4; i++) {
        int row = m0 + ty * 4 + i;
#pragma unroll
        for (int p = 0; p < 2; p++) {
            float re = c[i][2 * p];
            float im = c[i][2 * p + 1];
            float pw = fmaf(re, re, fmaf(im, im, 1e-14f));
            zxb[row * 512 + (n0 >> 1) + tx * 2 + p] = f2bf(logf(pw));
        }
    }
}

// ---------------- K2: fused conv1+conv2 via MFMA bf16 ----------------
// block (yt in 0..6, b); computes h2b[b, 0:256, y0..y0+31], y0 = 32*yt
// conv1: C1[k2=128][yy=32] = sum_dy w1[k2][dy] * zxb[b][dx][2(y0+yy)+dy]
// conv2: acc[k3=256][yy] += sum_k2 w2b[dx][k3][k2] * relu(C1[k2][yy])
__global__ __launch_bounds__(256, 3)
void k2_mfma(const ushort* __restrict__ zxb, const ushort* __restrict__ w1b,
             const ushort* __restrict__ w2b, ushort* __restrict__ h2b) {
    __shared__ ushort zl[25 * 4 * 200];   // [dx][copy c][200], copy c shifted by 2c elems
    __shared__ ushort h1l[16 * 32 * 8];   // [k2-chunk][yy][8]  (16B per (chunk,yy))
    const int t  = threadIdx.x;
    const int yt = blockIdx.x;
    const int b  = blockIdx.y;
    const int y0 = yt * 32;
    const int w  = t >> 6;      // wave 0..3
    const int l  = t & 63;
    const int yy = l & 31;      // MFMA n / m index
    const int q  = l >> 5;      // K-half select

    // ---- stage zx windows: zl[dx][c][i] = zxb[b][dx][2*y0 + 2c + i] (0 if OOB) ----
    for (int idx = t; idx < 25 * 4 * 192; idx += 256) {
        int i  = idx % 192;
        int dc = idx / 192;           // dx*4 + c
        int c  = dc & 3, dx = dc >> 2;
        int g  = 2 * y0 + 2 * c + i;
        ushort v = 0;
        if (g < 512) v = zxb[(b * 25 + dx) * 512 + g];
        zl[dc * 200 + i] = v;
    }

    // ---- persistent conv1 A-frags (w1, k2-tile = wave) ----
    s8v w1f[8];
    {
        const ushort* wp = w1b + (32 * w + yy) * 128 + 8 * q;
#pragma unroll
        for (int ks = 0; ks < 8; ks++)
            w1f[ks] = *(const s8v*)(wp + 16 * ks);
    }

    f16v acc2[2];
#pragma unroll
    for (int r = 0; r < 16; r++) { acc2[0][r] = 0.f; acc2[1][r] = 0.f; }

    __syncthreads();

    // conv1 B-frag base: copy c = yy&3; elem = 8*(yy>>2) + 16*ks + 8*q
    const int c_    = yy & 3;
    const int zbase = c_ * 200 + 8 * (yy >> 2) + 8 * q;

    for (int dx = 0; dx < 25; dx++) {
        // ---- conv1 ----
        f16v a1;
#pragma unroll
        for (int r = 0; r < 16; r++) a1[r] = 0.f;
        const ushort* zp = zl + dx * 800 + zbase;
#pragma unroll
        for (int ks = 0; ks < 8; ks++) {
            s8v bf = *(const s8v*)(zp + 16 * ks);
            a1 = __builtin_amdgcn_mfma_f32_32x32x16_bf16(w1f[ks], bf, a1, 0, 0, 0);
        }
        __syncthreads();   // conv2 of previous dx done with h1l
        // relu + pack to bf16, write C/D rows (4 contiguous k2 per reg-group)
#pragma unroll
        for (int g = 0; g < 4; g++) {
            unsigned p0 = (unsigned)f2bf(fmaxf(a1[4 * g + 0], 0.f))
                        | ((unsigned)f2bf(fmaxf(a1[4 * g + 1], 0.f)) << 16);
            unsigned p1 = (unsigned)f2bf(fmaxf(a1[4 * g + 2], 0.f))
                        | ((unsigned)f2bf(fmaxf(a1[4 * g + 3], 0.f)) << 16);
            // k2 = 32w + 8g + 4q + (0..3) -> chunk 4w+g, offset 4q
            unsigned* dst = (unsigned*)(h1l + ((4 * w + g) * 32 + yy) * 8 + 4 * q);
            dst[0] = p0; dst[1] = p1;
        }
        __syncthreads();   // h1l ready
        // ---- conv2 ----
        const ushort* ap = w2b + ((size_t)dx * 256 + yy) * 128 + 8 * q;
#pragma unroll
        for (int ks = 0; ks < 8; ks++) {
            s8v hb  = *(const s8v*)(h1l + ((2 * ks + q) * 32 + yy) * 8);
            s8v af0 = *(const s8v*)(ap + (2 * w + 0) * 4096 + 16 * ks);
            s8v af1 = *(const s8v*)(ap + (2 * w + 1) * 4096 + 16 * ks);
            acc2[0] = __builtin_amdgcn_mfma_f32_32x32x16_bf16(af0, hb, acc2[0], 0, 0, 0);
            acc2[1] = __builtin_amdgcn_mfma_f32_32x32x16_bf16(af1, hb, acc2[1], 0, 0, 0);
        }
    }

    // ---- store h2 (relu, bf16) ----
    int y = y0 + yy;
    if (y < 193) {
#pragma unroll
        for (int mt = 0; mt < 2; mt++) {
            int k3base = 32 * (2 * w + mt);
#pragma unroll
            for (int r = 0; r < 16; r++) {
                int k3 = k3base + (r & 3) + 8 * (r >> 2) + 4 * q;
                h2b[(b * 256 + k3) * 193 + y] = f2bf(fmaxf(acc2[mt][r], 0.f));
            }
        }
    }
}

// ---------------- K4: y partials = h2(128x49408) @ beta^T, k-split 128 ----------------
__global__ __launch_bounds__(256)
void k4_beta(const ushort* __restrict__ h2, const float* __restrict__ beta,
             float* __restrict__ part) {
    __shared__ float As[2 * 132];
    __shared__ float Bs[2 * 132];
    const int t  = threadIdx.x;
    const int s  = blockIdx.x;     // 0..127
    const int ks = s * 386;
    const int lrow = t >> 1;
    const int lkk  = t & 1;
    const int tx = t & 15, ty = t >> 4;

    float acc[8][8];
#pragma unroll
    for (int i = 0; i < 8; i++)
#pragma unroll
        for (int j = 0; j < 8; j++) acc[i][j] = 0.f;

    const ushort* hrow = h2   + (size_t)lrow * 49408 + ks + lkk;
    const float*  brow = beta + (size_t)lrow * 49408 + ks + lkk;

    for (int c0 = 0; c0 < 386; c0 += 2) {
        __syncthreads();
        As[lkk * 132 + lrow] = bf2f(hrow[c0]);
        Bs[lkk * 132 + lrow] = brow[c0];
        __syncthreads();
#pragma unroll
        for (int kk = 0; kk < 2; kk++) {
            float4 a0 = *(const float4*)&As[kk * 132 + ty * 8];
            float4 a1 = *(const float4*)&As[kk * 132 + ty * 8 + 4];
            float4 b0 = *(const float4*)&Bs[kk * 132 + tx * 8];
            float4 b1 = *(const float4*)&Bs[kk * 132 + tx * 8 + 4];
            float a[8] = {a0.x, a0.y, a0.z, a0.w, a1.x, a1.y, a1.z, a1.w};
            float b[8] = {b0.x, b0.y, b0.z, b0.w, b1.x, b1.y, b1.z, b1.w};
#pragma unroll
            for (int i = 0; i < 8; i++)
#pragma unroll
                for (int j = 0; j < 8; j++)
                    acc[i][j] = fmaf(a[i], b[j], acc[i][j]);
        }
    }
    float* pp = part + (size_t)s * 16384;
#pragma unroll
    for (int i = 0; i < 8; i++)
#pragma unroll
        for (int j = 0; j < 8; j++)
            pp[(ty * 8 + i) * 128 + tx * 8 + j] = acc[i][j];
}

// ---------------- K5: reduce partials ----------------
__global__ void k5_red(const float* __restrict__ part, float* __restrict__ out) {
    int i = blockIdx.x * 256 + threadIdx.x;
    float s = 0.f;
    for (int k = 0; k < 128; k++) s += part[(size_t)k * 16384 + i];
    out[i] = s;
}

extern "C" void kernel_launch(void* const* d_in, const int* in_sizes, int n_in,
                              void* d_out, int out_size, void* d_ws, size_t ws_size,
                              hipStream_t stream) {
    const float* x    = (const float*)d_in[0];
    const float* filt = (const float*)d_in[1];
    const float* w1   = (const float*)d_in[2];
    const float* w2   = (const float*)d_in[3];
    const float* beta = (const float*)d_in[4];
    float* out = (float*)d_out;

    char* ws = (char*)d_ws;
    ushort* zxb  = (ushort*)(ws + 0);
    ushort* h2b  = (ushort*)(ws + 3276800);
    ushort* w1b  = (ushort*)(ws + 15921152);
    ushort* w2b  = (ushort*)(ws + 15953920);
    float*  part = (float*)(ws + 17592320);

    k0a_w1b<<<64, 256, 0, stream>>>(w1, w1b);
    k0b_w2b<<<3200, 256, 0, stream>>>(w2, w2b);
    k1_spec<<<dim3(16, 50), 256, 0, stream>>>(x, filt, zxb);
    k2_mfma<<<dim3(7, 128), 256, 0, stream>>>(zxb, w1b, w2b, h2b);
    k4_beta<<<128, 256, 0, stream>>>(h2b, beta, part);
    k5_red<<<64, 256, 0, stream>>>(part, out);
}

// Round 3
// 472.766 us; speedup vs baseline: 3.9027x; 1.8668x over previous
//
#include <hip/hip_runtime.h>
#include <hip/hip_bf16.h>
#include <math.h>

// D=4096 K=512 HOP=512 WIN=16384 DX=25 B=128 K2=128 DY=128 K3=256 Y=193 M=128
// ws layout (bytes):
//   zxb  @ 0          : 128*25*512*2   = 3,276,800   (bf16 zx)
//   h2b  @ 3,276,800  : 128*256*193*2  = 12,644,352  (bf16 h2)
//   w1b  @ 15,921,152 : 32,768                      (bf16 w1 [k2][dy])
//   w2b  @ 15,953,920 : 1,638,400                   (bf16 w2 [dx][k3][k2])
//   bb   @ 17,592,320 : 128*49408*2    = 12,648,448 (bf16 beta)
//   xh   @ 30,240,768 : 128*16384*2    = 4,194,304  (fp16 x)       } dead after K1
//   fB   @ 34,435,072 : 4096*1024*2    = 8,388,608  (fp16 filt)    }
//   part @ 30,240,768 : 193*16384*4    = 12,648,448 (aliases xh/fB; used after K1)
// total 42,889,216 B (<= 43.5 MB used in round 1)

typedef __attribute__((ext_vector_type(8))) short s8v;       // 8 bf16
typedef __attribute__((ext_vector_type(8))) _Float16 half8;  // 8 fp16
typedef __attribute__((ext_vector_type(16))) float f16v;     // 32x32 acc

__device__ inline ushort f2bf(float f) {
    union { float f; unsigned u; } v; v.f = f;
    unsigned u = v.u;
    return (ushort)((u + 0x7FFFu + ((u >> 16) & 1u)) >> 16);
}

// ---------------- K0x: x -> fp16 ----------------
__global__ void k0x_xh(const float* __restrict__ x, _Float16* __restrict__ xh) {
    int i = blockIdx.x * 256 + threadIdx.x;   // 0..2097151
    xh[i] = (_Float16)x[i];
}

// ---------------- K0f: filt (4096x1024) -> fp16 tiled [k/8][n][8] ----------------
__global__ __launch_bounds__(256)
void k0f_fB(const float* __restrict__ filt, _Float16* __restrict__ fB) {
    __shared__ float tile[8][257];
    const int t   = threadIdx.x;
    const int n0  = blockIdx.x * 256;   // 0..3
    const int kc8 = blockIdx.y;         // 0..511
    for (int idx = t; idx < 8 * 256; idx += 256) {
        int kk = idx >> 8, n = idx & 255;
        tile[kk][n] = filt[(kc8 * 8 + kk) * 1024 + n0 + n];
    }
    __syncthreads();
    half8 v;
#pragma unroll
    for (int j = 0; j < 8; j++) v[j] = (_Float16)tile[j][t];
    *(half8*)(fB + (size_t)kc8 * 8192 + (size_t)(n0 + t) * 8) = v;
}

// ---------------- K0a: w1 -> bf16 [k2][dy] ----------------
__global__ void k0a_w1b(const float* __restrict__ w1, ushort* __restrict__ w1b) {
    int i = blockIdx.x * 256 + threadIdx.x;
    w1b[i] = f2bf(w1[i]);
}

// ---------------- K0b: w2 (K3,K2,DX) -> bf16 [dx][k3][k2] ----------------
__global__ void k0b_w2b(const float* __restrict__ w2, ushort* __restrict__ w2b) {
    int i = blockIdx.x * 256 + threadIdx.x;
    int k2 = i & 127;
    int k3 = (i >> 7) & 255;
    int dx = i >> 15;
    w2b[i] = f2bf(w2[(k3 * 128 + k2) * 25 + dx]);
}

// ---------------- K0c: beta -> bf16 ----------------
__global__ void k0c_bb(const float* __restrict__ beta, ushort* __restrict__ bb) {
    int i = blockIdx.x * 256 + threadIdx.x;   // 0..6324223
    bb[i] = f2bf(beta[i]);
}

// ---------------- K1: spec GEMM via fp16 MFMA + |.|^2 + log -> zxb ----------------
// C(3200x1024) = W(3200x4096) @ F(4096x1024); block tile 128x128, 4 waves 64x64
__global__ __launch_bounds__(256)
void k1_mfma(const _Float16* __restrict__ xh, const _Float16* __restrict__ fB,
             ushort* __restrict__ zxb) {
    __shared__ _Float16 Al[4096];   // [s][row][q][8]; byte addr = s*4096 + row*32 + q*16
    const int t  = threadIdx.x;
    const int n0 = blockIdx.x * 128;
    const int m0 = blockIdx.y * 128;
    const int w  = t >> 6, l = t & 63;
    const int wm = (w >> 1) * 64, wn = (w & 1) * 64;
    const int qf = l >> 5;
    const int ml = l & 31;

    // A staging: thread t covers LDS chunk t (s=0) and 256+t (s=1)
    const int srow = t >> 1;       // 0..127
    const int sq   = t & 1;
    const int gm   = m0 + srow;
    const _Float16* apt = xh + (gm / 25) * 16384 + (gm % 25) * 512 + sq * 8;
    half8* Als8 = (half8*)Al;

    // B direct-global frag pointer (frag-contiguous layout)
    const _Float16* pB = fB + ((size_t)qf * 1024 + (size_t)(n0 + wn + ml)) * 8;

    f16v acc[2][2];
#pragma unroll
    for (int i = 0; i < 2; i++)
#pragma unroll
        for (int j = 0; j < 2; j++)
#pragma unroll
            for (int r = 0; r < 16; r++) acc[i][j][r] = 0.f;

    for (int kb = 0; kb < 128; kb++) {
        half8 v0 = *(const half8*)(apt + kb * 32);        // s=0 chunk
        half8 v1 = *(const half8*)(apt + kb * 32 + 16);   // s=1 chunk
        __syncthreads();
        Als8[t]       = v0;
        Als8[256 + t] = v1;
        __syncthreads();
#pragma unroll
        for (int s = 0; s < 2; s++) {
            half8 a0 = *(const half8*)((const char*)Al + s * 4096 + (wm + ml) * 32 + qf * 16);
            half8 a1 = *(const half8*)((const char*)Al + s * 4096 + (wm + 32 + ml) * 32 + qf * 16);
            const _Float16* pBk = pB + ((size_t)kb * 2 + s) * 16384;
            half8 b0 = *(const half8*)(pBk);
            half8 b1 = *(const half8*)(pBk + 256);
            acc[0][0] = __builtin_amdgcn_mfma_f32_32x32x16_f16(a0, b0, acc[0][0], 0, 0, 0);
            acc[0][1] = __builtin_amdgcn_mfma_f32_32x32x16_f16(a0, b1, acc[0][1], 0, 0, 0);
            acc[1][0] = __builtin_amdgcn_mfma_f32_32x32x16_f16(a1, b0, acc[1][0], 0, 0, 0);
            acc[1][1] = __builtin_amdgcn_mfma_f32_32x32x16_f16(a1, b1, acc[1][1], 0, 0, 0);
        }
    }

    // epilogue: adjacent cols (re,im) live in lane pairs -> shfl_xor(1)
#pragma unroll
    for (int mt = 0; mt < 2; mt++)
#pragma unroll
        for (int nt = 0; nt < 2; nt++) {
#pragma unroll
            for (int r = 0; r < 16; r++) {
                float val = acc[mt][nt][r];
                float oth = __shfl_xor(val, 1, 64);
                if (!(l & 1)) {
                    float pw = fmaf(val, val, fmaf(oth, oth, 1e-14f));
                    int m = m0 + wm + mt * 32 + 4 * qf + (r & 3) + 8 * (r >> 2);
                    int n = n0 + wn + nt * 32 + ml;
                    zxb[m * 512 + (n >> 1)] = f2bf(logf(pw));
                }
            }
        }
}

// ---------------- K2: fused conv1+conv2 via MFMA bf16 (unchanged) ----------------
__global__ __launch_bounds__(256, 3)
void k2_mfma(const ushort* __restrict__ zxb, const ushort* __restrict__ w1b,
             const ushort* __restrict__ w2b, ushort* __restrict__ h2b) {
    __shared__ ushort zl[25 * 4 * 200];
    __shared__ ushort h1l[16 * 32 * 8];
    const int t  = threadIdx.x;
    const int yt = blockIdx.x;
    const int b  = blockIdx.y;
    const int y0 = yt * 32;
    const int w  = t >> 6;
    const int l  = t & 63;
    const int yy = l & 31;
    const int q  = l >> 5;

    for (int idx = t; idx < 25 * 4 * 192; idx += 256) {
        int i  = idx % 192;
        int dc = idx / 192;
        int c  = dc & 3, dx = dc >> 2;
        int g  = 2 * y0 + 2 * c + i;
        ushort v = 0;
        if (g < 512) v = zxb[(b * 25 + dx) * 512 + g];
        zl[dc * 200 + i] = v;
    }

    s8v w1f[8];
    {
        const ushort* wp = w1b + (32 * w + yy) * 128 + 8 * q;
#pragma unroll
        for (int ks = 0; ks < 8; ks++)
            w1f[ks] = *(const s8v*)(wp + 16 * ks);
    }

    f16v acc2[2];
#pragma unroll
    for (int r = 0; r < 16; r++) { acc2[0][r] = 0.f; acc2[1][r] = 0.f; }

    __syncthreads();

    const int c_    = yy & 3;
    const int zbase = c_ * 200 + 8 * (yy >> 2) + 8 * q;

    for (int dx = 0; dx < 25; dx++) {
        f16v a1;
#pragma unroll
        for (int r = 0; r < 16; r++) a1[r] = 0.f;
        const ushort* zp = zl + dx * 800 + zbase;
#pragma unroll
        for (int ks = 0; ks < 8; ks++) {
            s8v bf = *(const s8v*)(zp + 16 * ks);
            a1 = __builtin_amdgcn_mfma_f32_32x32x16_bf16(w1f[ks], bf, a1, 0, 0, 0);
        }
        __syncthreads();
#pragma unroll
        for (int g = 0; g < 4; g++) {
            unsigned p0 = (unsigned)f2bf(fmaxf(a1[4 * g + 0], 0.f))
                        | ((unsigned)f2bf(fmaxf(a1[4 * g + 1], 0.f)) << 16);
            unsigned p1 = (unsigned)f2bf(fmaxf(a1[4 * g + 2], 0.f))
                        | ((unsigned)f2bf(fmaxf(a1[4 * g + 3], 0.f)) << 16);
            unsigned* dst = (unsigned*)(h1l + ((4 * w + g) * 32 + yy) * 8 + 4 * q);
            dst[0] = p0; dst[1] = p1;
        }
        __syncthreads();
        const ushort* ap = w2b + ((size_t)dx * 256 + yy) * 128 + 8 * q;
#pragma unroll
        for (int ks = 0; ks < 8; ks++) {
            s8v hb  = *(const s8v*)(h1l + ((2 * ks + q) * 32 + yy) * 8);
            s8v af0 = *(const s8v*)(ap + (2 * w + 0) * 4096 + 16 * ks);
            s8v af1 = *(const s8v*)(ap + (2 * w + 1) * 4096 + 16 * ks);
            acc2[0] = __builtin_amdgcn_mfma_f32_32x32x16_bf16(af0, hb, acc2[0], 0, 0, 0);
            acc2[1] = __builtin_amdgcn_mfma_f32_32x32x16_bf16(af1, hb, acc2[1], 0, 0, 0);
        }
    }

    int y = y0 + yy;
    if (y < 193) {
#pragma unroll
        for (int mt = 0; mt < 2; mt++) {
            int k3base = 32 * (2 * w + mt);
#pragma unroll
            for (int r = 0; r < 16; r++) {
                int k3 = k3base + (r & 3) + 8 * (r >> 2) + 4 * q;
                h2b[(b * 256 + k3) * 193 + y] = f2bf(fmaxf(acc2[mt][r], 0.f));
            }
        }
    }
}

// ---------------- K4: y partials via bf16 MFMA, 193-way k-split ----------------
// block s: k in [s*256, s*256+256); wave w: batch rows w*32..+32, all 128 cols
__global__ __launch_bounds__(256)
void k4_mfma(const ushort* __restrict__ h2b, const ushort* __restrict__ bb,
             float* __restrict__ part) {
    const int t = threadIdx.x, w = t >> 6, l = t & 63;
    const int s = blockIdx.x;      // 0..192
    const int kb = s * 256;
    const int qf = l >> 5;
    const int ml = l & 31;
    const ushort* pa  = h2b + (size_t)(w * 32 + ml) * 49408 + kb + qf * 8;
    const ushort* pb0 = bb  + (size_t)ml * 49408 + kb + qf * 8;

    f16v acc[4];
#pragma unroll
    for (int nt = 0; nt < 4; nt++)
#pragma unroll
        for (int r = 0; r < 16; r++) acc[nt][r] = 0.f;

    for (int ks = 0; ks < 16; ks++) {
        s8v af = *(const s8v*)(pa + ks * 16);
#pragma unroll
        for (int nt = 0; nt < 4; nt++) {
            s8v bf = *(const s8v*)(pb0 + (size_t)nt * 32 * 49408 + ks * 16);
            acc[nt] = __builtin_amdgcn_mfma_f32_32x32x16_bf16(af, bf, acc[nt], 0, 0, 0);
        }
    }
    float* pp = part + (size_t)s * 16384;
#pragma unroll
    for (int nt = 0; nt < 4; nt++)
#pragma unroll
        for (int r = 0; r < 16; r++) {
            int m = w * 32 + 4 * qf + (r & 3) + 8 * (r >> 2);
            pp[m * 128 + nt * 32 + ml] = acc[nt][r];
        }
}

// ---------------- K5: reduce 193 partials ----------------
__global__ void k5_red(const float* __restrict__ part, float* __restrict__ out) {
    int i = blockIdx.x * 256 + threadIdx.x;
    float s = 0.f;
    for (int k = 0; k < 193; k++) s += part[(size_t)k * 16384 + i];
    out[i] = s;
}

extern "C" void kernel_launch(void* const* d_in, const int* in_sizes, int n_in,
                              void* d_out, int out_size, void* d_ws, size_t ws_size,
                              hipStream_t stream) {
    const float* x    = (const float*)d_in[0];
    const float* filt = (const float*)d_in[1];
    const float* w1   = (const float*)d_in[2];
    const float* w2   = (const float*)d_in[3];
    const float* beta = (const float*)d_in[4];
    float* out = (float*)d_out;

    char* ws = (char*)d_ws;
    ushort*   zxb  = (ushort*)(ws + 0);
    ushort*   h2b  = (ushort*)(ws + 3276800);
    ushort*   w1b  = (ushort*)(ws + 15921152);
    ushort*   w2b  = (ushort*)(ws + 15953920);
    ushort*   bb   = (ushort*)(ws + 17592320);
    _Float16* xh   = (_Float16*)(ws + 30240768);
    _Float16* fB   = (_Float16*)(ws + 34435072);
    float*    part = (float*)(ws + 30240768);   // aliases xh/fB (dead after K1)

    k0x_xh<<<8192, 256, 0, stream>>>(x, xh);
    k0f_fB<<<dim3(4, 512), 256, 0, stream>>>(filt, fB);
    k0a_w1b<<<64, 256, 0, stream>>>(w1, w1b);
    k0b_w2b<<<3200, 256, 0, stream>>>(w2, w2b);
    k0c_bb<<<24704, 256, 0, stream>>>(beta, bb);
    k1_mfma<<<dim3(8, 25), 256, 0, stream>>>(xh, fB, zxb);
    k2_mfma<<<dim3(7, 128), 256, 0, stream>>>(zxb, w1b, w2b, h2b);
    k4_mfma<<<193, 256, 0, stream>>>(h2b, bb, part);
    k5_red<<<64, 256, 0, stream>>>(part, out);
}

// Round 4
// 365.798 us; speedup vs baseline: 5.0439x; 1.2924x over previous
//
#include <hip/hip_runtime.h>
#include <hip/hip_bf16.h>
#include <math.h>

// D=4096 K=512 HOP=512 WIN=16384 DX=25 B=128 K2=128 DY=128 K3=256 Y=193 M=128
// ws layout (bytes):
//   zxb  @ 0          : 128*25*512*2   = 3,276,800   (bf16 zx)
//   h2b  @ 3,276,800  : 128*256*193*2  = 12,644,352  (bf16 h2)
//   w1b  @ 15,921,152 : 32,768                      (bf16 w1 [k2][dy])
//   w2c  @ 15,953,920 : 1,638,400                   (bf16 w2 [k3][dx*128+k2])
//   bb   @ 17,592,320 : 128*49408*2    = 12,648,448 (bf16 beta)
//   xh   @ 30,240,768 : 128*16384*2    = 4,194,304  (fp16 x)       } dead after K1
//   fB   @ 34,435,072 : 4096*1024*2    = 8,388,608  (fp16 filt)    }
//   part @ 30,240,768 : 193*16384*4    = 12,648,448 (aliases xh/fB; used after K1)

typedef __attribute__((ext_vector_type(8))) short s8v;       // 8 bf16
typedef __attribute__((ext_vector_type(8))) _Float16 half8;  // 8 fp16
typedef __attribute__((ext_vector_type(16))) float f16v;     // 32x32 acc

__device__ inline ushort f2bf(float f) {
    union { float f; unsigned u; } v; v.f = f;
    unsigned u = v.u;
    return (ushort)((u + 0x7FFFu + ((u >> 16) & 1u)) >> 16);
}

// ---------------- K0x: x -> fp16 ----------------
__global__ void k0x_xh(const float* __restrict__ x, _Float16* __restrict__ xh) {
    int i = blockIdx.x * 256 + threadIdx.x;
    xh[i] = (_Float16)x[i];
}

// ---------------- K0f: filt (4096x1024) -> fp16 tiled [k/8][n][8] ----------------
__global__ __launch_bounds__(256)
void k0f_fB(const float* __restrict__ filt, _Float16* __restrict__ fB) {
    __shared__ float tile[8][257];
    const int t   = threadIdx.x;
    const int n0  = blockIdx.x * 256;
    const int kc8 = blockIdx.y;
    for (int idx = t; idx < 8 * 256; idx += 256) {
        int kk = idx >> 8, n = idx & 255;
        tile[kk][n] = filt[(kc8 * 8 + kk) * 1024 + n0 + n];
    }
    __syncthreads();
    half8 v;
#pragma unroll
    for (int j = 0; j < 8; j++) v[j] = (_Float16)tile[j][t];
    *(half8*)(fB + (size_t)kc8 * 8192 + (size_t)(n0 + t) * 8) = v;
}

// ---------------- K0a: w1 -> bf16 [k2][dy] ----------------
__global__ void k0a_w1b(const float* __restrict__ w1, ushort* __restrict__ w1b) {
    int i = blockIdx.x * 256 + threadIdx.x;
    w1b[i] = f2bf(w1[i]);
}

// ---------------- K0b: w2 (K3,K2,DX) -> bf16 [k3][dx*128+k2] ----------------
__global__ void k0b_w2c(const float* __restrict__ w2, ushort* __restrict__ w2c) {
    int i = blockIdx.x * 256 + threadIdx.x;   // 0..819199
    int k2 = i & 127;
    int dx = (i >> 7) % 25;
    int k3 = i / 3200;
    w2c[i] = f2bf(w2[(k3 * 128 + k2) * 25 + dx]);
}

// ---------------- K0c: beta -> bf16 ----------------
__global__ void k0c_bb(const float* __restrict__ beta, ushort* __restrict__ bb) {
    int i = blockIdx.x * 256 + threadIdx.x;
    bb[i] = f2bf(beta[i]);
}

// ---------------- K1: spec GEMM via fp16 MFMA + |.|^2 + log -> zxb ----------------
__global__ __launch_bounds__(256)
void k1_mfma(const _Float16* __restrict__ xh, const _Float16* __restrict__ fB,
             ushort* __restrict__ zxb) {
    __shared__ _Float16 Al[4096];
    const int t  = threadIdx.x;
    const int n0 = blockIdx.x * 128;
    const int m0 = blockIdx.y * 128;
    const int w  = t >> 6, l = t & 63;
    const int wm = (w >> 1) * 64, wn = (w & 1) * 64;
    const int qf = l >> 5;
    const int ml = l & 31;

    const int srow = t >> 1;
    const int sq   = t & 1;
    const int gm   = m0 + srow;
    const _Float16* apt = xh + (gm / 25) * 16384 + (gm % 25) * 512 + sq * 8;
    half8* Als8 = (half8*)Al;

    const _Float16* pB = fB + ((size_t)qf * 1024 + (size_t)(n0 + wn + ml)) * 8;

    f16v acc[2][2];
#pragma unroll
    for (int i = 0; i < 2; i++)
#pragma unroll
        for (int j = 0; j < 2; j++)
#pragma unroll
            for (int r = 0; r < 16; r++) acc[i][j][r] = 0.f;

    for (int kb = 0; kb < 128; kb++) {
        half8 v0 = *(const half8*)(apt + kb * 32);
        half8 v1 = *(const half8*)(apt + kb * 32 + 16);
        __syncthreads();
        Als8[t]       = v0;
        Als8[256 + t] = v1;
        __syncthreads();
#pragma unroll
        for (int s = 0; s < 2; s++) {
            half8 a0 = *(const half8*)((const char*)Al + s * 4096 + (wm + ml) * 32 + qf * 16);
            half8 a1 = *(const half8*)((const char*)Al + s * 4096 + (wm + 32 + ml) * 32 + qf * 16);
            const _Float16* pBk = pB + ((size_t)kb * 2 + s) * 16384;
            half8 b0 = *(const half8*)(pBk);
            half8 b1 = *(const half8*)(pBk + 256);
            acc[0][0] = __builtin_amdgcn_mfma_f32_32x32x16_f16(a0, b0, acc[0][0], 0, 0, 0);
            acc[0][1] = __builtin_amdgcn_mfma_f32_32x32x16_f16(a0, b1, acc[0][1], 0, 0, 0);
            acc[1][0] = __builtin_amdgcn_mfma_f32_32x32x16_f16(a1, b0, acc[1][0], 0, 0, 0);
            acc[1][1] = __builtin_amdgcn_mfma_f32_32x32x16_f16(a1, b1, acc[1][1], 0, 0, 0);
        }
    }

#pragma unroll
    for (int mt = 0; mt < 2; mt++)
#pragma unroll
        for (int nt = 0; nt < 2; nt++) {
#pragma unroll
            for (int r = 0; r < 16; r++) {
                float val = acc[mt][nt][r];
                float oth = __shfl_xor(val, 1, 64);
                if (!(l & 1)) {
                    float pw = fmaf(val, val, fmaf(oth, oth, 1e-14f));
                    int m = m0 + wm + mt * 32 + 4 * qf + (r & 3) + 8 * (r >> 2);
                    int n = n0 + wn + nt * 32 + ml;
                    zxb[m * 512 + (n >> 1)] = f2bf(logf(pw));
                }
            }
        }
}

// ---------------- K2: fused conv1+conv2, chunked-dx (3), y-tile 64 ----------------
// grid (4 yt, 128 b), 4 waves. LDS: zl dbuf (2x3dx x 4 copies x 272) + h1l (3dx).
#define ZPITCH 272
__global__ __launch_bounds__(256, 2)
void k2_mfma(const ushort* __restrict__ zxb, const ushort* __restrict__ w1b,
             const ushort* __restrict__ w2c, ushort* __restrict__ h2b) {
    __shared__ ushort zl[2 * 3 * 4 * ZPITCH];   // 13,056 B
    __shared__ ushort h1l[3 * 16 * 64 * 8];     // 49,152 B
    const int t  = threadIdx.x;
    const int yt = blockIdx.x;      // 0..3
    const int b  = blockIdx.y;
    const int y0 = yt * 64;
    const int w  = t >> 6;
    const int l  = t & 63;
    const int yy = l & 31;
    const int q  = l >> 5;

    // persistent conv1 A-frags (w1): wave w owns k2 in [32w, 32w+32)
    s8v w1f[8];
    {
        const ushort* wp = w1b + (32 * w + yy) * 128 + 8 * q;
#pragma unroll
        for (int ks = 0; ks < 8; ks++)
            w1f[ks] = *(const s8v*)(wp + 16 * ks);
    }

    f16v acc[2][2];
#pragma unroll
    for (int mt = 0; mt < 2; mt++)
#pragma unroll
        for (int nt = 0; nt < 2; nt++)
#pragma unroll
            for (int r = 0; r < 16; r++) acc[mt][nt][r] = 0.f;

    // ---- initial stage: chunk 0 -> buf 0 ----
    {
        const int nq = 3 * 4 * 62;
        for (int idx = t; idx < nq; idx += 256) {
            int iq = idx % 62;
            int dc = idx / 62;
            int c = dc & 3, d = dc >> 2;
            const ushort* src = zxb + ((b * 25 + d) << 9);
            int gg = 2 * y0 + 2 * c + 4 * iq;
            ushort* dst = zl + (d * 4 + c) * ZPITCH + 4 * iq;
#pragma unroll
            for (int u = 0; u < 4; u++) {
                int g = gg + u;
                dst[u] = (g < 512) ? src[g] : (ushort)0;
            }
        }
    }

    for (int ch = 0; ch < 9; ch++) {
        const int p  = ch & 1;
        const int nd = (ch == 8) ? 1 : 3;
        __syncthreads();   // zl[p] staged, h1l free (prev conv2 done)

        // ---- prefetch loads for chunk ch+1 into regs ----
        ushort pv[12];
        int nq2 = 0;
        if (ch < 8) {
            const int nd2 = (ch == 7) ? 1 : 3;
            nq2 = nd2 * 4 * 62;
#pragma unroll
            for (int r = 0; r < 3; r++) {
                int idx = t + r * 256;
                if (idx < nq2) {
                    int iq = idx % 62;
                    int dc = idx / 62;
                    int c = dc & 3, d = dc >> 2;
                    const ushort* src = zxb + ((b * 25 + (ch + 1) * 3 + d) << 9);
                    int gg = 2 * y0 + 2 * c + 4 * iq;
#pragma unroll
                    for (int u = 0; u < 4; u++) {
                        int g = gg + u;
                        pv[r * 4 + u] = (g < 512) ? src[g] : (ushort)0;
                    }
                }
            }
        }

        // ---- conv1: h1[d][k2][ye] for this chunk ----
        for (int d = 0; d < nd; d++) {
            const int zb = (p * 3 + d) * 4;
#pragma unroll
            for (int nt = 0; nt < 2; nt++) {
                const int ye = nt * 32 + yy;
                const ushort* zp = zl + (zb + (ye & 3)) * ZPITCH + 8 * (ye >> 2) + 8 * q;
                f16v a1;
#pragma unroll
                for (int r = 0; r < 16; r++) a1[r] = 0.f;
#pragma unroll
                for (int ks = 0; ks < 8; ks++) {
                    s8v bf = *(const s8v*)(zp + 16 * ks);
                    a1 = __builtin_amdgcn_mfma_f32_32x32x16_bf16(w1f[ks], bf, a1, 0, 0, 0);
                }
                // relu + pack: k2 = 32w + 8g + 4q + r  -> h1l[d][4w+g][ye][4q+r]
#pragma unroll
                for (int g = 0; g < 4; g++) {
                    unsigned p0 = (unsigned)f2bf(fmaxf(a1[4 * g + 0], 0.f))
                                | ((unsigned)f2bf(fmaxf(a1[4 * g + 1], 0.f)) << 16);
                    unsigned p1 = (unsigned)f2bf(fmaxf(a1[4 * g + 2], 0.f))
                                | ((unsigned)f2bf(fmaxf(a1[4 * g + 3], 0.f)) << 16);
                    unsigned* dst = (unsigned*)(h1l + (((d * 16 + 4 * w + g) * 64) + ye) * 8 + 4 * q);
                    dst[0] = p0; dst[1] = p1;
                }
            }
        }

        // ---- write prefetched zl[1-p] ----
        if (ch < 8) {
#pragma unroll
            for (int r = 0; r < 3; r++) {
                int idx = t + r * 256;
                if (idx < nq2) {
                    int iq = idx % 62;
                    int dc = idx / 62;
                    int c = dc & 3, d = dc >> 2;
                    ushort* dst = zl + (((1 - p) * 3 + d) * 4 + c) * ZPITCH + 4 * iq;
#pragma unroll
                    for (int u = 0; u < 4; u++) dst[u] = pv[r * 4 + u];
                }
            }
        }

        __syncthreads();   // h1l ready

        // ---- conv2: acc[mt][nt] += w2[k3][dx,k2] * h1 ----
        for (int d = 0; d < nd; d++) {
            const int dxa = ch * 3 + d;
            const ushort* ap = w2c + (size_t)(64 * w + yy) * 3200 + dxa * 128 + 8 * q;
#pragma unroll
            for (int ks = 0; ks < 8; ks++) {
                s8v a0 = *(const s8v*)(ap + 16 * ks);
                s8v a1f = *(const s8v*)(ap + (size_t)32 * 3200 + 16 * ks);
#pragma unroll
                for (int nt = 0; nt < 2; nt++) {
                    s8v hb = *(const s8v*)(h1l + (((d * 16 + 2 * ks + q) * 64) + nt * 32 + yy) * 8);
                    acc[0][nt] = __builtin_amdgcn_mfma_f32_32x32x16_bf16(a0, hb, acc[0][nt], 0, 0, 0);
                    acc[1][nt] = __builtin_amdgcn_mfma_f32_32x32x16_bf16(a1f, hb, acc[1][nt], 0, 0, 0);
                }
            }
        }
    }

    // ---- epilogue: store h2b (relu) ----
#pragma unroll
    for (int mt = 0; mt < 2; mt++)
#pragma unroll
        for (int nt = 0; nt < 2; nt++) {
            int y = y0 + nt * 32 + yy;
            if (y < 193) {
#pragma unroll
                for (int r = 0; r < 16; r++) {
                    int k3 = 64 * w + 32 * mt + (r & 3) + 8 * (r >> 2) + 4 * q;
                    h2b[(b * 256 + k3) * 193 + y] = f2bf(fmaxf(acc[mt][nt][r], 0.f));
                }
            }
        }
}

// ---------------- K4: y partials via bf16 MFMA, 193-way k-split ----------------
__global__ __launch_bounds__(256)
void k4_mfma(const ushort* __restrict__ h2b, const ushort* __restrict__ bb,
             float* __restrict__ part) {
    const int t = threadIdx.x, w = t >> 6, l = t & 63;
    const int s = blockIdx.x;
    const int kb = s * 256;
    const int qf = l >> 5;
    const int ml = l & 31;
    const ushort* pa  = h2b + (size_t)(w * 32 + ml) * 49408 + kb + qf * 8;
    const ushort* pb0 = bb  + (size_t)ml * 49408 + kb + qf * 8;

    f16v acc[4];
#pragma unroll
    for (int nt = 0; nt < 4; nt++)
#pragma unroll
        for (int r = 0; r < 16; r++) acc[nt][r] = 0.f;

    for (int ks = 0; ks < 16; ks++) {
        s8v af = *(const s8v*)(pa + ks * 16);
#pragma unroll
        for (int nt = 0; nt < 4; nt++) {
            s8v bf = *(const s8v*)(pb0 + (size_t)nt * 32 * 49408 + ks * 16);
            acc[nt] = __builtin_amdgcn_mfma_f32_32x32x16_bf16(af, bf, acc[nt], 0, 0, 0);
        }
    }
    float* pp = part + (size_t)s * 16384;
#pragma unroll
    for (int nt = 0; nt < 4; nt++)
#pragma unroll
        for (int r = 0; r < 16; r++) {
            int m = w * 32 + 4 * qf + (r & 3) + 8 * (r >> 2);
            pp[m * 128 + nt * 32 + ml] = acc[nt][r];
        }
}

// ---------------- K5: reduce 193 partials ----------------
__global__ void k5_red(const float* __restrict__ part, float* __restrict__ out) {
    int i = blockIdx.x * 256 + threadIdx.x;
    float s = 0.f;
    for (int k = 0; k < 193; k++) s += part[(size_t)k * 16384 + i];
    out[i] = s;
}

extern "C" void kernel_launch(void* const* d_in, const int* in_sizes, int n_in,
                              void* d_out, int out_size, void* d_ws, size_t ws_size,
                              hipStream_t stream) {
    const float* x    = (const float*)d_in[0];
    const float* filt = (const float*)d_in[1];
    const float* w1   = (const float*)d_in[2];
    const float* w2   = (const float*)d_in[3];
    const float* beta = (const float*)d_in[4];
    float* out = (float*)d_out;

    char* ws = (char*)d_ws;
    ushort*   zxb  = (ushort*)(ws + 0);
    ushort*   h2b  = (ushort*)(ws + 3276800);
    ushort*   w1b  = (ushort*)(ws + 15921152);
    ushort*   w2c  = (ushort*)(ws + 15953920);
    ushort*   bb   = (ushort*)(ws + 17592320);
    _Float16* xh   = (_Float16*)(ws + 30240768);
    _Float16* fB   = (_Float16*)(ws + 34435072);
    float*    part = (float*)(ws + 30240768);

    k0x_xh<<<8192, 256, 0, stream>>>(x, xh);
    k0f_fB<<<dim3(4, 512), 256, 0, stream>>>(filt, fB);
    k0a_w1b<<<64, 256, 0, stream>>>(w1, w1b);
    k0b_w2c<<<3200, 256, 0, stream>>>(w2, w2c);
    k0c_bb<<<24704, 256, 0, stream>>>(beta, bb);
    k1_mfma<<<dim3(8, 25), 256, 0, stream>>>(xh, fB, zxb);
    k2_mfma<<<dim3(4, 128), 256, 0, stream>>>(zxb, w1b, w2c, h2b);
    k4_mfma<<<193, 256, 0, stream>>>(h2b, bb, part);
    k5_red<<<64, 256, 0, stream>>>(part, out);
}